// Round 2
// baseline (1052.590 us; speedup 1.0000x reference)
//
#include <hip/hip_runtime.h>
#include <stdint.h>
#include <stddef.h>

// NASCell fused: new_m,new_c = gates(x@Wx, m_prev@Wm, c_prev)
// B=8192, I=H=1024, 8H=8192. Outputs fp32: new_m at [0,8.4M), new_c at [8.4M,16.8M).
//
// V3 structure: NO LDS, NO barriers in the main loop.
//   prep_b : weights -> fp16 hi/lo split, laid out as per-(hblk,kt) 32KB tiles
//            of 32 fragment slabs (1KB each, lane-ordered): slab index
//            (mat*8+g)*2+hl, byte = lane*16. A wave's B-fragment load is one
//            fully-coalesced global_load_dwordx4 from a contiguous 1KB slab.
//   split_ab: x,m_prev -> xh/xl/mh/ml fp16 row-major (one kernel, grid.y=2).
// Main kernel reads B fragments straight from ws (L2-resident: all 32
// row-blocks sharing hblk land on XCD hblk%8 because grid.x=64 round-robins
// XCDs with stride 8; all 4 waves of a block read identical slabs -> L1 hits).
// Waves run fully independent -> no per-kt vmcnt(0)/barrier drain.
// Arithmetic identical to V1/V2 (3-pass hh/hl/lh fp16 MFMA, fp32 accum).

typedef _Float16 half8 __attribute__((ext_vector_type(8)));
typedef float f32x4 __attribute__((ext_vector_type(4)));
typedef float float4v __attribute__((ext_vector_type(4)));
typedef unsigned int u32;
typedef u32 u32x4 __attribute__((ext_vector_type(4)));

__device__ __forceinline__ float fsig(float x) { return 1.0f / (1.0f + __expf(-x)); }
__device__ __forceinline__ float ftanh(float x) { return 2.0f * fsig(2.0f * x) - 1.0f; }
__device__ __forceinline__ u32 packh(_Float16 a, _Float16 b) {
  union { u32 u; _Float16 h[2]; } p;
  p.h[0] = a; p.h[1] = b; return p.u;
}

// ---------------------------------------------------------------------------
// prep_b: build per-(hblk,kt) 32KB fragment-tile images of the weights.
// Tile at wsB + (hblk*32 + kt)*32768.
// Slab layout: ((mat*8+g)*2 + hl)*1024 bytes; within slab, lane l holds 16B =
// 8 fp16 for MFMA B-fragment: lane (q=l>>4, n=l&15) -> k = q*8+j, col n.
// Thread (mat,g,n) gathers 32 k-rows of col n (coalesced 64B per 16 lanes)
// and scatters 4+4 contiguous 16B chunks (256B per 16-lane group).
// ---------------------------------------------------------------------------
__global__ __launch_bounds__(256) void prep_b(
    const float* __restrict__ w_inputs, const float* __restrict__ w_m,
    char* __restrict__ wsB) {
  const int kt = blockIdx.x;    // 0..31
  const int hblk = blockIdx.y;  // 0..63
  const int tid = threadIdx.x;
  const int n = tid & 15;
  const int g = (tid >> 4) & 7;
  const int mat = tid >> 7;
  const float* w = mat ? w_m : w_inputs;
  const float* src = w + (size_t)kt * 32 * 8192 + (size_t)g * 1024 + hblk * 16 + n;
  _Float16 hs[32], ls[32];
#pragma unroll
  for (int k = 0; k < 32; ++k) {
    const float v = src[(size_t)k * 8192];
    const _Float16 h = (_Float16)v;
    hs[k] = h;
    ls[k] = (_Float16)(v - (float)h);
  }
  char* tile = wsB + ((size_t)hblk * 32 + kt) * 32768;
  char* hi = tile + (size_t)((mat * 8 + g) * 2 + 0) * 1024;
  char* lo = hi + 1024;
#pragma unroll
  for (int kc = 0; kc < 4; ++kc) {
    u32x4 a = {packh(hs[kc * 8 + 0], hs[kc * 8 + 1]), packh(hs[kc * 8 + 2], hs[kc * 8 + 3]),
               packh(hs[kc * 8 + 4], hs[kc * 8 + 5]), packh(hs[kc * 8 + 6], hs[kc * 8 + 7])};
    *(u32x4*)(hi + (kc * 16 + n) * 16) = a;
    u32x4 b = {packh(ls[kc * 8 + 0], ls[kc * 8 + 1]), packh(ls[kc * 8 + 2], ls[kc * 8 + 3]),
               packh(ls[kc * 8 + 4], ls[kc * 8 + 5]), packh(ls[kc * 8 + 6], ls[kc * 8 + 7])};
    *(u32x4*)(lo + (kc * 16 + n) * 16) = b;
  }
}

// ---------------------------------------------------------------------------
// split_ab: elementwise fp32 -> (hi fp16, lo fp16) for x (blockIdx.y=0) and
// m_prev (blockIdx.y=1). 8 elems/thread.
// ---------------------------------------------------------------------------
__global__ __launch_bounds__(256) void split_ab(
    const float4v* __restrict__ xin, const float4v* __restrict__ min,
    half8* __restrict__ xhi, half8* __restrict__ xlo,
    half8* __restrict__ mhi, half8* __restrict__ mlo) {
  const int which = blockIdx.y;
  const float4v* in = which ? min : xin;
  half8* hi = which ? mhi : xhi;
  half8* lo = which ? mlo : xlo;
  const size_t idx = (size_t)blockIdx.x * 256 + threadIdx.x;  // 1,048,576 per array
  const float4v a = in[idx * 2];
  const float4v b = in[idx * 2 + 1];
  half8 h, l;
#pragma unroll
  for (int j = 0; j < 4; ++j) {
    const float v = a[j]; const _Float16 hv = (_Float16)v;
    h[j] = hv; l[j] = (_Float16)(v - (float)hv);
  }
#pragma unroll
  for (int j = 0; j < 4; ++j) {
    const float v = b[j]; const _Float16 hv = (_Float16)v;
    h[4 + j] = hv; l[4 + j] = (_Float16)(v - (float)hv);
  }
  hi[idx] = h; lo[idx] = l;
}

// ---------------------------------------------------------------------------
// Main kernel V3: 256 rows x 16 h-cols per block, 16x16x32 f16 MFMA, 3-pass
// two-term split. B fragments loaded directly from ws slabs (no LDS, no
// __syncthreads). Gates j!=3 concat-K accumulate; gate 3 separate x/m acc.
// ---------------------------------------------------------------------------
__global__ __launch_bounds__(256, 2) void nascell_v3(
    const _Float16* __restrict__ xh_g, const _Float16* __restrict__ xl_g,
    const _Float16* __restrict__ mh_g, const _Float16* __restrict__ ml_g,
    const char* __restrict__ wsB,
    const float* __restrict__ c_prev,
    float* __restrict__ out) {
  const int tid = threadIdx.x;
  const int wid = tid >> 6;
  const int lane = tid & 63;
  const int row0 = blockIdx.y * 256;
  const int hblk = blockIdx.x;
  const int m16 = lane & 15;
  const int q = lane >> 4;

  const size_t arow = (size_t)(row0 + wid * 64 + m16);
  const _Float16* xhb = xh_g + arow * 1024 + q * 8;
  const _Float16* xlb = xl_g + arow * 1024 + q * 8;
  const _Float16* mhb = mh_g + arow * 1024 + q * 8;
  const _Float16* mlb = ml_g + arow * 1024 + q * 8;

  // per-lane fragment base: tile stream for this hblk, lane's 16B within slab
  const char* bt = wsB + (size_t)hblk * 32 * 32768 + lane * 16;

  f32x4 acc[4][9];
#pragma unroll
  for (int r = 0; r < 4; ++r)
#pragma unroll
    for (int gg = 0; gg < 9; ++gg) acc[r][gg] = (f32x4)0.0f;

#pragma unroll 1
  for (int kt = 0; kt < 32; ++kt) {
    const char* tb = bt + (size_t)kt * 32768;

    // A fragment loads (already-split fp16, 16B each; LLC-resident)
    half8 axh[4], axl[4], amh[4], aml[4];
#pragma unroll
    for (int r = 0; r < 4; ++r) {
      axh[r] = *(const half8*)(xhb + (size_t)r * 16384 + kt * 32);
      axl[r] = *(const half8*)(xlb + (size_t)r * 16384 + kt * 32);
      amh[r] = *(const half8*)(mhb + (size_t)r * 16384 + kt * 32);
      aml[r] = *(const half8*)(mlb + (size_t)r * 16384 + kt * 32);
    }

    // ---- x-pass: acc += xh*Bh + xh*Bl + xl*Bh (mat 0 slabs) ----
#pragma unroll
    for (int c = 0; c < 8; ++c) {
      const half8 bxh = *(const half8*)(tb + (size_t)(c * 2) * 1024);
      const half8 bxl = *(const half8*)(tb + (size_t)(c * 2 + 1) * 1024);
#pragma unroll
      for (int r = 0; r < 4; ++r) {
        f32x4 t = acc[r][c];
        t = __builtin_amdgcn_mfma_f32_16x16x32_f16(axh[r], bxh, t, 0, 0, 0);
        t = __builtin_amdgcn_mfma_f32_16x16x32_f16(axh[r], bxl, t, 0, 0, 0);
        t = __builtin_amdgcn_mfma_f32_16x16x32_f16(axl[r], bxh, t, 0, 0, 0);
        acc[r][c] = t;
      }
    }

    // ---- m-pass: gate c!=3 adds into acc[r][c]; gate 3 -> acc[r][8] ----
#pragma unroll
    for (int c = 0; c < 8; ++c) {
      const half8 bmh = *(const half8*)(tb + 16384 + (size_t)(c * 2) * 1024);
      const half8 bml = *(const half8*)(tb + 16384 + (size_t)(c * 2 + 1) * 1024);
      const int tgt = (c == 3) ? 8 : c;
#pragma unroll
      for (int r = 0; r < 4; ++r) {
        f32x4 t = acc[r][tgt];
        t = __builtin_amdgcn_mfma_f32_16x16x32_f16(amh[r], bmh, t, 0, 0, 0);
        t = __builtin_amdgcn_mfma_f32_16x16x32_f16(amh[r], bml, t, 0, 0, 0);
        t = __builtin_amdgcn_mfma_f32_16x16x32_f16(aml[r], bmh, t, 0, 0, 0);
        acc[r][tgt] = t;
      }
    }
  }

  // ---- epilogue: per-lane gate combine, fp32 outputs (unchanged) ----
  float* out_m = out;
  float* out_c = out + (size_t)8192 * 1024;
  const int h = hblk * 16 + m16;
#pragma unroll
  for (int r = 0; r < 4; ++r) {
#pragma unroll
    for (int i = 0; i < 4; ++i) {
      const int grow = row0 + wid * 64 + r * 16 + q * 4 + i;
      const float p0 = acc[r][0][i], p1 = acc[r][1][i], p2 = acc[r][2][i];
      const float x3 = acc[r][3][i], p4 = acc[r][4][i], p5 = acc[r][5][i];
      const float p6 = acc[r][6][i], p7 = acc[r][7][i], m3 = acc[r][8][i];
      const float cp = c_prev[(size_t)grow * 1024 + h];
      float l1_0 = fsig(p0);
      float l1_1 = fmaxf(p1, 0.0f);
      float l1_2 = fsig(p2);
      float l1_3 = fmaxf(x3 * m3, 0.0f);
      float l1_4 = ftanh(p4);
      float l1_5 = fsig(p5);
      float l1_6 = ftanh(p6);
      float l1_7 = fsig(p7);
      float l2_0 = ftanh(l1_0 * l1_1);
      float l2_1 = ftanh(l1_2 + l1_3);
      float l2_2 = ftanh(l1_4 * l1_5);
      float l2_3 = fsig(l1_6 + l1_7);
      float l2_0b = ftanh(l2_0 + cp);
      float nc = l2_0b * l2_1;
      float l3_1 = ftanh(l2_2 + l2_3);
      float nm = ftanh(nc * l3_1);
      out_m[(size_t)grow * 1024 + h] = nm;
      out_c[(size_t)grow * 1024 + h] = nc;
    }
  }
}

// ---------------------------------------------------------------------------
// Legacy kernel (V1) — fallback when ws_size < 128 MB. Unchanged.
// ---------------------------------------------------------------------------
__global__ __launch_bounds__(256, 2) void nascell_main(
    const float* __restrict__ x,
    const float* __restrict__ m_prev,
    const float* __restrict__ c_prev,
    const float* __restrict__ w_inputs,
    const float* __restrict__ w_m,
    float* __restrict__ out) {
  __shared__ short lds[17408];
  const int tid = threadIdx.x;
  const int wid = tid >> 6;
  const int lane = tid & 63;
  const int row0 = blockIdx.y * 256;
  const int h0 = blockIdx.x * 16;
  const int m16 = lane & 15;
  const int q = lane >> 4;

  const int bmat = tid >> 7;
  const int bg = (tid >> 4) & 7;
  const int bkp = (tid & 15) * 2;
  const float* wsrc = bmat ? w_m : w_inputs;
  const float* wrow_base = wsrc + (size_t)bkp * 8192 + (size_t)bg * 1024 + (size_t)h0;
  short* bh = lds + bmat * 4352 + bg * 544 + (bkp ^ ((bg & 3) << 3));
  short* bl = bh + 8704;

  const float* axp[4];
  const float* amp[4];
#pragma unroll
  for (int r = 0; r < 4; ++r) {
    const size_t arow = (size_t)(row0 + wid * 64 + r * 16 + m16);
    axp[r] = x + arow * 1024 + q * 8;
    amp[r] = m_prev + arow * 1024 + q * 8;
  }

  f32x4 acc[4][9];
#pragma unroll
  for (int r = 0; r < 4; ++r)
#pragma unroll
    for (int gg = 0; gg < 9; ++gg) acc[r][gg] = (f32x4)0.0f;

  for (int kt = 0; kt < 32; ++kt) {
    const float* wr = wrow_base + (size_t)kt * 32 * 8192;
    float4v b0 = *(const float4v*)(wr);
    float4v b1 = *(const float4v*)(wr + 4);
    float4v b2 = *(const float4v*)(wr + 8);
    float4v b3 = *(const float4v*)(wr + 12);
    float4v d0 = *(const float4v*)(wr + 8192);
    float4v d1 = *(const float4v*)(wr + 8196);
    float4v d2 = *(const float4v*)(wr + 8200);
    float4v d3 = *(const float4v*)(wr + 8204);

    float4v xa[4][2];
#pragma unroll
    for (int r = 0; r < 4; ++r) {
      xa[r][0] = *(const float4v*)(axp[r] + kt * 32);
      xa[r][1] = *(const float4v*)(axp[r] + kt * 32 + 4);
    }

    __syncthreads();

#pragma unroll
    for (int n = 0; n < 16; ++n) {
      const float r0 = (n < 4 ? b0[n & 3] : n < 8 ? b1[n & 3] : n < 12 ? b2[n & 3] : b3[n & 3]);
      const float r1 = (n < 4 ? d0[n & 3] : n < 8 ? d1[n & 3] : n < 12 ? d2[n & 3] : d3[n & 3]);
      const _Float16 h0v = (_Float16)r0;
      const _Float16 h1v = (_Float16)r1;
      *(u32*)(bh + n * 32) = packh(h0v, h1v);
      const _Float16 l0v = (_Float16)(r0 - (float)h0v);
      const _Float16 l1v = (_Float16)(r1 - (float)h1v);
      *(u32*)(bl + n * 32) = packh(l0v, l1v);
    }

    half8 axh[4], axl[4];
#pragma unroll
    for (int r = 0; r < 4; ++r)
#pragma unroll
      for (int j = 0; j < 8; ++j) {
        const float v = xa[r][j >> 2][j & 3];
        const _Float16 hv = (_Float16)v;
        axh[r][j] = hv;
        axl[r][j] = (_Float16)(v - (float)hv);
      }

    __syncthreads();

    float4v ma[4][2];
#pragma unroll
    for (int r = 0; r < 4; ++r) {
      ma[r][0] = *(const float4v*)(amp[r] + kt * 32);
      ma[r][1] = *(const float4v*)(amp[r] + kt * 32 + 4);
    }

#pragma unroll
    for (int c = 0; c < 8; ++c) {
      const int qs = (q ^ (c & 3)) * 8;
      const int bo = c * 544 + m16 * 32 + qs;
      half8 bxh = *(const half8*)(lds + bo);
      half8 bxl = *(const half8*)(lds + 8704 + bo);
#pragma unroll
      for (int r = 0; r < 4; ++r) {
        f32x4 t = acc[r][c];
        t = __builtin_amdgcn_mfma_f32_16x16x32_f16(axh[r], bxh, t, 0, 0, 0);
        t = __builtin_amdgcn_mfma_f32_16x16x32_f16(axh[r], bxl, t, 0, 0, 0);
        t = __builtin_amdgcn_mfma_f32_16x16x32_f16(axl[r], bxh, t, 0, 0, 0);
        acc[r][c] = t;
      }
    }

    half8 amh[4], aml[4];
#pragma unroll
    for (int r = 0; r < 4; ++r)
#pragma unroll
      for (int j = 0; j < 8; ++j) {
        const float v = ma[r][j >> 2][j & 3];
        const _Float16 hv = (_Float16)v;
        amh[r][j] = hv;
        aml[r][j] = (_Float16)(v - (float)hv);
      }

#pragma unroll
    for (int c = 0; c < 8; ++c) {
      const int qs = (q ^ (c & 3)) * 8;
      const int bo = 4352 + c * 544 + m16 * 32 + qs;
      half8 bmh = *(const half8*)(lds + bo);
      half8 bml = *(const half8*)(lds + 8704 + bo);
      const int tgt = (c == 3) ? 8 : c;
#pragma unroll
      for (int r = 0; r < 4; ++r) {
        f32x4 t = acc[r][tgt];
        t = __builtin_amdgcn_mfma_f32_16x16x32_f16(amh[r], bmh, t, 0, 0, 0);
        t = __builtin_amdgcn_mfma_f32_16x16x32_f16(amh[r], bml, t, 0, 0, 0);
        t = __builtin_amdgcn_mfma_f32_16x16x32_f16(aml[r], bmh, t, 0, 0, 0);
        acc[r][tgt] = t;
      }
    }
  }

  float* out_m = out;
  float* out_c = out + (size_t)8192 * 1024;
  const int h = h0 + m16;
#pragma unroll
  for (int r = 0; r < 4; ++r) {
#pragma unroll
    for (int i = 0; i < 4; ++i) {
      const int grow = row0 + wid * 64 + r * 16 + q * 4 + i;
      const float p0 = acc[r][0][i], p1 = acc[r][1][i], p2 = acc[r][2][i];
      const float x3 = acc[r][3][i], p4 = acc[r][4][i], p5 = acc[r][5][i];
      const float p6 = acc[r][6][i], p7 = acc[r][7][i], m3 = acc[r][8][i];
      const float cp = c_prev[(size_t)grow * 1024 + h];
      float l1_0 = fsig(p0);
      float l1_1 = fmaxf(p1, 0.0f);
      float l1_2 = fsig(p2);
      float l1_3 = fmaxf(x3 * m3, 0.0f);
      float l1_4 = ftanh(p4);
      float l1_5 = fsig(p5);
      float l1_6 = ftanh(p6);
      float l1_7 = fsig(p7);
      float l2_0 = ftanh(l1_0 * l1_1);
      float l2_1 = ftanh(l1_2 + l1_3);
      float l2_2 = ftanh(l1_4 * l1_5);
      float l2_3 = fsig(l1_6 + l1_7);
      float l2_0b = ftanh(l2_0 + cp);
      float nc = l2_0b * l2_1;
      float l3_1 = ftanh(l2_2 + l2_3);
      float nm = ftanh(nc * l3_1);
      out_m[(size_t)grow * 1024 + h] = nm;
      out_c[(size_t)grow * 1024 + h] = nc;
    }
  }
}

extern "C" void kernel_launch(void* const* d_in, const int* in_sizes, int n_in,
                              void* d_out, int out_size, void* d_ws, size_t ws_size,
                              hipStream_t stream) {
  (void)in_sizes; (void)n_in; (void)out_size;
  const float* x        = (const float*)d_in[0];
  const float* m_prev   = (const float*)d_in[1];
  const float* c_prev   = (const float*)d_in[2];
  const float* w_m      = (const float*)d_in[3];
  const float* w_inputs = (const float*)d_in[4];
  float* out = (float*)d_out;

  // ws layout: [0,64MB) B fragment tiles; then xh,xl,mh,ml (16MB each) = 128MB.
  if (ws_size >= 134217728ull && d_ws != nullptr) {
    char* wsB = (char*)d_ws;
    _Float16* xh = (_Float16*)((char*)d_ws + 67108864);
    _Float16* xl = xh + 8388608;
    _Float16* mh = xl + 8388608;
    _Float16* ml = mh + 8388608;
    prep_b<<<dim3(32, 64), 256, 0, stream>>>(w_inputs, w_m, wsB);
    split_ab<<<dim3(4096, 2), 256, 0, stream>>>(
        (const float4v*)x, (const float4v*)m_prev,
        (half8*)xh, (half8*)xl, (half8*)mh, (half8*)ml);
    nascell_v3<<<dim3(64, 32), 256, 0, stream>>>(xh, xl, mh, ml, wsB, c_prev, out);
  } else {
    dim3 grid(64, 32);
    nascell_main<<<grid, 256, 0, stream>>>(x, m_prev, c_prev, w_inputs, w_m, out);
  }
}